// Round 3
// baseline (220.881 us; speedup 1.0000x reference)
//
#include <hip/hip_runtime.h>

// Problem dims: B=16, Q=64, K=512, DQ=DK=DV=512, H=256
#define LOG2E 1.4426950408889634f
#define TWO_LOG2E 2.8853900817779268f

__device__ __forceinline__ float e2x(float v) {
    // exp2(2*log2(e)*v) == e^{2v}
    return __builtin_amdgcn_exp2f(v * TWO_LOG2E);
}

// ---------------------------------------------------------------------------
// Kernel 0: zero d_out (harness poisons it to 0xAA; pv accumulates atomically)
// ---------------------------------------------------------------------------
__global__ __launch_bounds__(256) void zero_out_kernel(float4* __restrict__ out) {
    out[(size_t)blockIdx.x * 256 + threadIdx.x] = make_float4(0.f, 0.f, 0.f, 0.f);
}

// ---------------------------------------------------------------------------
// Kernel 1a: Eq[1024][256] = exp2(c * (queries[1024][512] @ Wq[512][256]))
// 64x64 tile, 256 threads, 4x4 micro-tile, K-chunk 32, reg-prefetch dbuf.
// ---------------------------------------------------------------------------
__global__ __launch_bounds__(256) void proj_q_kernel(const float* __restrict__ A,
                                                     const float* __restrict__ W,
                                                     float* __restrict__ C) {
    __shared__ float As[32][68];
    __shared__ float Ws[32][68];
    const int t  = threadIdx.x;
    const int m0 = blockIdx.x * 64;
    const int n0 = blockIdx.y * 64;
    const int mr = (t & 15) * 4;
    const int nr = (t >> 4) * 4;

    float acc[4][4];
#pragma unroll
    for (int i = 0; i < 4; ++i)
#pragma unroll
        for (int j = 0; j < 4; ++j) acc[i][j] = 0.0f;

    float4 ra[2], rw[2];
#pragma unroll
    for (int p = 0; p < 2; ++p) {
        int u = t + p * 256;
        ra[p] = *reinterpret_cast<const float4*>(&A[(size_t)(m0 + (u >> 3)) * 512 + (u & 7) * 4]);
        rw[p] = *reinterpret_cast<const float4*>(&W[(size_t)(u >> 4) * 256 + n0 + (u & 15) * 4]);
    }

    for (int c = 0; c < 16; ++c) {
#pragma unroll
        for (int p = 0; p < 2; ++p) {
            int u  = t + p * 256;
            int m  = u >> 3;
            int d4 = (u & 7) * 4;
            As[d4 + 0][m] = ra[p].x; As[d4 + 1][m] = ra[p].y;
            As[d4 + 2][m] = ra[p].z; As[d4 + 3][m] = ra[p].w;
            *reinterpret_cast<float4*>(&Ws[u >> 4][(u & 15) * 4]) = rw[p];
        }
        __syncthreads();
        if (c < 15) {
            int d0 = (c + 1) * 32;
#pragma unroll
            for (int p = 0; p < 2; ++p) {
                int u = t + p * 256;
                ra[p] = *reinterpret_cast<const float4*>(&A[(size_t)(m0 + (u >> 3)) * 512 + d0 + (u & 7) * 4]);
                rw[p] = *reinterpret_cast<const float4*>(&W[(size_t)(d0 + (u >> 4)) * 256 + n0 + (u & 15) * 4]);
            }
        }
#pragma unroll
        for (int d = 0; d < 32; ++d) {
            float4 a4 = *reinterpret_cast<const float4*>(&As[d][mr]);
            float4 b4 = *reinterpret_cast<const float4*>(&Ws[d][nr]);
            float av[4] = {a4.x, a4.y, a4.z, a4.w};
            float bv[4] = {b4.x, b4.y, b4.z, b4.w};
#pragma unroll
            for (int i = 0; i < 4; ++i)
#pragma unroll
                for (int j = 0; j < 4; ++j)
                    acc[i][j] = fmaf(av[i], bv[j], acc[i][j]);
        }
        __syncthreads();
    }
#pragma unroll
    for (int i = 0; i < 4; ++i) {
        float4 o;
        o.x = e2x(acc[i][0]); o.y = e2x(acc[i][1]);
        o.z = e2x(acc[i][2]); o.w = e2x(acc[i][3]);
        *reinterpret_cast<float4*>(&C[(size_t)(m0 + mr + i) * 256 + n0 + nr]) = o;
    }
}

// ---------------------------------------------------------------------------
// Kernel 1b: Ekp[b][h2][k][2] = exp2(c * (keys[b] @ Wk)^T), h-pair interleaved.
// Same GEMM + reg-prefetch; epilogue transposes in LDS, exp2, pair layout.
// ---------------------------------------------------------------------------
__global__ __launch_bounds__(256) void proj_k_kernel(const float* __restrict__ A,
                                                     const float* __restrict__ W,
                                                     float* __restrict__ CT) {
    __shared__ float smem[4352];   // As[32][68] + Ws[32][68]; reused as Cs[64][68]
    float (*As)[68] = reinterpret_cast<float(*)[68]>(smem);
    float (*Ws)[68] = reinterpret_cast<float(*)[68]>(smem + 2176);
    const int t  = threadIdx.x;
    const int m0 = blockIdx.x * 64;   // flat (b,k) row base
    const int n0 = blockIdx.y * 64;   // h base
    const int mr = (t & 15) * 4;
    const int nr = (t >> 4) * 4;

    float acc[4][4];
#pragma unroll
    for (int i = 0; i < 4; ++i)
#pragma unroll
        for (int j = 0; j < 4; ++j) acc[i][j] = 0.0f;

    float4 ra[2], rw[2];
#pragma unroll
    for (int p = 0; p < 2; ++p) {
        int u = t + p * 256;
        ra[p] = *reinterpret_cast<const float4*>(&A[(size_t)(m0 + (u >> 3)) * 512 + (u & 7) * 4]);
        rw[p] = *reinterpret_cast<const float4*>(&W[(size_t)(u >> 4) * 256 + n0 + (u & 15) * 4]);
    }

    for (int c = 0; c < 16; ++c) {
#pragma unroll
        for (int p = 0; p < 2; ++p) {
            int u  = t + p * 256;
            int m  = u >> 3;
            int d4 = (u & 7) * 4;
            As[d4 + 0][m] = ra[p].x; As[d4 + 1][m] = ra[p].y;
            As[d4 + 2][m] = ra[p].z; As[d4 + 3][m] = ra[p].w;
            *reinterpret_cast<float4*>(&Ws[u >> 4][(u & 15) * 4]) = rw[p];
        }
        __syncthreads();
        if (c < 15) {
            int d0 = (c + 1) * 32;
#pragma unroll
            for (int p = 0; p < 2; ++p) {
                int u = t + p * 256;
                ra[p] = *reinterpret_cast<const float4*>(&A[(size_t)(m0 + (u >> 3)) * 512 + d0 + (u & 7) * 4]);
                rw[p] = *reinterpret_cast<const float4*>(&W[(size_t)(d0 + (u >> 4)) * 256 + n0 + (u & 15) * 4]);
            }
        }
#pragma unroll
        for (int d = 0; d < 32; ++d) {
            float4 a4 = *reinterpret_cast<const float4*>(&As[d][mr]);
            float4 b4 = *reinterpret_cast<const float4*>(&Ws[d][nr]);
            float av[4] = {a4.x, a4.y, a4.z, a4.w};
            float bv[4] = {b4.x, b4.y, b4.z, b4.w};
#pragma unroll
            for (int i = 0; i < 4; ++i)
#pragma unroll
                for (int j = 0; j < 4; ++j)
                    acc[i][j] = fmaf(av[i], bv[j], acc[i][j]);
        }
        __syncthreads();   // also protects smem reuse as Cs below
    }
    // transpose in LDS: Cs[n(h)][m(k)]
    float (*Cs)[68] = reinterpret_cast<float(*)[68]>(smem);
#pragma unroll
    for (int i = 0; i < 4; ++i)
#pragma unroll
        for (int j = 0; j < 4; ++j)
            Cs[nr + j][mr + i] = acc[i][j];
    __syncthreads();

    const int b      = m0 >> 9;
    const int k0h    = (m0 & 511) >> 1;  // k0/2 in float4-pair units
    const int h2base = n0 >> 1;
    float4* out4 = reinterpret_cast<float4*>(CT);
#pragma unroll
    for (int p = 0; p < 4; ++p) {
        int u   = t + p * 256;       // 0..1023
        int h2r = u >> 5;            // 0..31
        int kk  = (u & 31) * 2;      // 0..62, step 2
        float4 o;
        o.x = e2x(Cs[2 * h2r    ][kk    ]);
        o.y = e2x(Cs[2 * h2r + 1][kk    ]);
        o.z = e2x(Cs[2 * h2r    ][kk + 1]);
        o.w = e2x(Cs[2 * h2r + 1][kk + 1]);
        out4[(size_t)b * 32768 + (size_t)(h2base + h2r) * 256 + k0h + (u & 31)] = o;
    }
}

// ---------------------------------------------------------------------------
// Kernel 2: scores + masked softmax -> attn[b][q][k]   (unchanged this round)
// ---------------------------------------------------------------------------
__global__ __launch_bounds__(256) void score_softmax_kernel(
        const float* __restrict__ Eq, const float* __restrict__ Ekp,
        const float* __restrict__ Wv, const int* __restrict__ valid_lens,
        float* __restrict__ attn) {
    __shared__ float redmA[4], redmB[4], redlA[4], redlB[4];

    const int t  = threadIdx.x;
    const int bq = blockIdx.x;        // 0..511
    const int b  = bq >> 5;
    const int q0 = (bq & 31) * 2;

    const float* eqA = Eq + (size_t)(b * 64 + q0) * 256;
    const float* eqB = eqA + 256;
    const float4* ek4 = reinterpret_cast<const float4*>(Ekp) + (size_t)b * 32768 + t;

    float accA0 = 0.f, accA1 = 0.f, accB0 = 0.f, accB1 = 0.f;
#pragma unroll 4
    for (int h2 = 0; h2 < 128; ++h2) {
        const float4 ek = ek4[h2 * 256];
        const float w0 = Wv[2 * h2];
        const float w1 = Wv[2 * h2 + 1];
        {
            const float e0 = eqA[2 * h2], e1 = eqA[2 * h2 + 1];
            float a00 = fmaf(e0, ek.x, 1.0f);
            float a10 = fmaf(e1, ek.y, 1.0f);
            float a01 = fmaf(e0, ek.z, 1.0f);
            float a11 = fmaf(e1, ek.w, 1.0f);
            float d0 = a00 * a10, d1 = a01 * a11;
            float n0 = fmaf(w1, a00, w0 * a10);
            float n1 = fmaf(w1, a01, w0 * a11);
            accA0 = fmaf(n0, __builtin_amdgcn_rcpf(d0), accA0);
            accA1 = fmaf(n1, __builtin_amdgcn_rcpf(d1), accA1);
        }
        {
            const float e0 = eqB[2 * h2], e1 = eqB[2 * h2 + 1];
            float a00 = fmaf(e0, ek.x, 1.0f);
            float a10 = fmaf(e1, ek.y, 1.0f);
            float a01 = fmaf(e0, ek.z, 1.0f);
            float a11 = fmaf(e1, ek.w, 1.0f);
            float d0 = a00 * a10, d1 = a01 * a11;
            float n0 = fmaf(w1, a00, w0 * a10);
            float n1 = fmaf(w1, a01, w0 * a11);
            accB0 = fmaf(n0, __builtin_amdgcn_rcpf(d0), accB0);
            accB1 = fmaf(n1, __builtin_amdgcn_rcpf(d1), accB1);
        }
    }
    float sA0 = -2.0f * accA0, sA1 = -2.0f * accA1;
    float sB0 = -2.0f * accB0, sB1 = -2.0f * accB1;
    const int vl = valid_lens[b];
    const int k0 = 2 * t;
    if (k0     >= vl) { sA0 = -1e6f; sB0 = -1e6f; }
    if (k0 + 1 >= vl) { sA1 = -1e6f; sB1 = -1e6f; }

    const int w = t >> 6;
    float mA = fmaxf(sA0, sA1);
    float mB = fmaxf(sB0, sB1);
#pragma unroll
    for (int off = 32; off > 0; off >>= 1) {
        mA = fmaxf(mA, __shfl_xor(mA, off));
        mB = fmaxf(mB, __shfl_xor(mB, off));
    }
    if ((t & 63) == 0) { redmA[w] = mA; redmB[w] = mB; }
    __syncthreads();
    mA = fmaxf(fmaxf(redmA[0], redmA[1]), fmaxf(redmA[2], redmA[3]));
    mB = fmaxf(fmaxf(redmB[0], redmB[1]), fmaxf(redmB[2], redmB[3]));

    float pA0 = __builtin_amdgcn_exp2f((sA0 - mA) * LOG2E);
    float pA1 = __builtin_amdgcn_exp2f((sA1 - mA) * LOG2E);
    float pB0 = __builtin_amdgcn_exp2f((sB0 - mB) * LOG2E);
    float pB1 = __builtin_amdgcn_exp2f((sB1 - mB) * LOG2E);
    float lA = pA0 + pA1, lB = pB0 + pB1;
#pragma unroll
    for (int off = 32; off > 0; off >>= 1) {
        lA += __shfl_xor(lA, off);
        lB += __shfl_xor(lB, off);
    }
    if ((t & 63) == 0) { redlA[w] = lA; redlB[w] = lB; }
    __syncthreads();
    lA = (redlA[0] + redlA[1]) + (redlA[2] + redlA[3]);
    lB = (redlB[0] + redlB[1]) + (redlB[2] + redlB[3]);
    const float invA = 1.0f / lA;
    const float invB = 1.0f / lB;

    float2* attn2 = reinterpret_cast<float2*>(attn);
    float2 oA; oA.x = pA0 * invA; oA.y = pA1 * invA;
    float2 oB; oB.x = pB0 * invB; oB.y = pB1 * invB;
    attn2[(size_t)(b * 64 + q0) * 256 + t]       = oA;
    attn2[(size_t)(b * 64 + q0 + 1) * 256 + t]   = oB;
}

// ---------------------------------------------------------------------------
// Kernel 3: out += attn-chunk @ values-chunk  (k-split x4, atomicAdd epilogue)
// Block = (b, v-chunk 128, k-range 128) covering ALL 64 q -> values read once.
// 256 threads: thread = (q-group of 8) x (1 float4 of v); 32 fp32 acc.
// ---------------------------------------------------------------------------
__global__ __launch_bounds__(256) void pv_kernel(const float* __restrict__ attn,
                                                 const float* __restrict__ values,
                                                 float* __restrict__ out) {
    __shared__ float attnS[64][128];   // [q][k-chunk]  32 KB
    const int t   = threadIdx.x;
    const int b   = blockIdx.z;
    const int kb  = blockIdx.y * 128;  // k base
    const int v4b = blockIdx.x * 32;   // float4 col base (128 floats)
    const int kb4 = blockIdx.y * 32;

    const float4* attn4 = reinterpret_cast<const float4*>(attn);
#pragma unroll
    for (int p = 0; p < 8; ++p) {
        int u  = t + p * 256;          // 0..2047
        int qr = u >> 5;               // 0..63
        int c4 = u & 31;               // 0..31
        *reinterpret_cast<float4*>(&attnS[qr][c4 * 4]) =
            attn4[(size_t)(b * 64 + qr) * 128 + kb4 + c4];
    }
    __syncthreads();

    const int q0 = (t >> 5) * 8;       // 0,8,..,56
    const int v4 = v4b + (t & 31);     // float4 col index (0..127)
    const float4* val4 = reinterpret_cast<const float4*>(values)
                       + (size_t)(b * 512 + kb) * 128 + v4;

    float4 acc[8];
#pragma unroll
    for (int j = 0; j < 8; ++j) { acc[j].x = 0.f; acc[j].y = 0.f; acc[j].z = 0.f; acc[j].w = 0.f; }

#pragma unroll 2
    for (int kk = 0; kk < 128; kk += 2) {
        float4 vv0 = val4[(size_t)kk * 128];
        float4 vv1 = val4[(size_t)(kk + 1) * 128];
#pragma unroll
        for (int j = 0; j < 8; ++j) {
            float2 a = *reinterpret_cast<const float2*>(&attnS[q0 + j][kk]);
            acc[j].x = fmaf(a.x, vv0.x, acc[j].x);
            acc[j].y = fmaf(a.x, vv0.y, acc[j].y);
            acc[j].z = fmaf(a.x, vv0.z, acc[j].z);
            acc[j].w = fmaf(a.x, vv0.w, acc[j].w);
            acc[j].x = fmaf(a.y, vv1.x, acc[j].x);
            acc[j].y = fmaf(a.y, vv1.y, acc[j].y);
            acc[j].z = fmaf(a.y, vv1.z, acc[j].z);
            acc[j].w = fmaf(a.y, vv1.w, acc[j].w);
        }
    }

    float* outp = out + (size_t)(b * 64 + q0) * 512 + v4 * 4;
#pragma unroll
    for (int j = 0; j < 8; ++j) {
        atomicAdd(outp + (size_t)j * 512 + 0, acc[j].x);
        atomicAdd(outp + (size_t)j * 512 + 1, acc[j].y);
        atomicAdd(outp + (size_t)j * 512 + 2, acc[j].z);
        atomicAdd(outp + (size_t)j * 512 + 3, acc[j].w);
    }
}

// ---------------------------------------------------------------------------
extern "C" void kernel_launch(void* const* d_in, const int* in_sizes, int n_in,
                              void* d_out, int out_size, void* d_ws, size_t ws_size,
                              hipStream_t stream) {
    (void)in_sizes; (void)n_in; (void)out_size; (void)ws_size;
    const float* queries    = (const float*)d_in[0];   // [16,64,512]
    const float* keys       = (const float*)d_in[1];   // [16,512,512]
    const float* values     = (const float*)d_in[2];   // [16,512,512]
    const int*   valid_lens = (const int*)d_in[3];     // [16]
    const float* Wq         = (const float*)d_in[4];   // [512,256]
    const float* Wk         = (const float*)d_in[5];   // [512,256]
    const float* Wv         = (const float*)d_in[6];   // [256]
    float* out = (float*)d_out;                        // [16,64,512]

    float* ws   = (float*)d_ws;
    float* Eq   = ws;                        // [1024][256]              1 MB
    float* Ekp  = ws + 262144;               // [16][128][512][2]        8 MB
    float* attn = ws + 262144 + 2097152;     // [16][64][512]            2 MB

    hipLaunchKernelGGL(zero_out_kernel, dim3(512), dim3(256), 0, stream, (float4*)out);
    hipLaunchKernelGGL(proj_q_kernel, dim3(16, 4), dim3(256), 0, stream, queries, Wq, Eq);
    hipLaunchKernelGGL(proj_k_kernel, dim3(128, 4), dim3(256), 0, stream, keys, Wk, Ekp);
    hipLaunchKernelGGL(score_softmax_kernel, dim3(512), dim3(256), 0, stream,
                       Eq, Ekp, Wv, valid_lens, attn);
    hipLaunchKernelGGL(pv_kernel, dim3(4, 4, 16), dim3(256), 0, stream, attn, values, out);
}

// Round 4
// 188.736 us; speedup vs baseline: 1.1703x; 1.1703x over previous
//
#include <hip/hip_runtime.h>

// Problem dims: B=16, Q=64, K=512, DQ=DK=DV=512, H=256
#define LOG2E 1.4426950408889634f
#define TWO_LOG2E 2.8853900817779268f

__device__ __forceinline__ float e2x(float v) {
    // exp2(2*log2(e)*v) == e^{2v}
    return __builtin_amdgcn_exp2f(v * TWO_LOG2E);
}

// ---------------------------------------------------------------------------
// Kernel 1a: Eq[1024][256] = exp2(c * (queries[1024][512] @ Wq[512][256]))
// 64x64 tile, 256 threads, 4x4 micro-tile, K-chunk 32.  (round-2 version)
// ---------------------------------------------------------------------------
__global__ __launch_bounds__(256) void proj_q_kernel(const float* __restrict__ A,
                                                     const float* __restrict__ W,
                                                     float* __restrict__ C) {
    __shared__ float As[32][68];
    __shared__ float Ws[32][68];
    const int t  = threadIdx.x;
    const int m0 = blockIdx.x * 64;
    const int n0 = blockIdx.y * 64;
    const int mr = (t & 15) * 4;
    const int nr = (t >> 4) * 4;

    float acc[4][4];
#pragma unroll
    for (int i = 0; i < 4; ++i)
#pragma unroll
        for (int j = 0; j < 4; ++j) acc[i][j] = 0.0f;

    for (int d0 = 0; d0 < 512; d0 += 32) {
#pragma unroll
        for (int p = 0; p < 2; ++p) {
            int u  = t + p * 256;
            int m  = u >> 3;
            int d4 = (u & 7) * 4;
            float4 a = *reinterpret_cast<const float4*>(&A[(size_t)(m0 + m) * 512 + d0 + d4]);
            As[d4 + 0][m] = a.x; As[d4 + 1][m] = a.y;
            As[d4 + 2][m] = a.z; As[d4 + 3][m] = a.w;
        }
#pragma unroll
        for (int p = 0; p < 2; ++p) {
            int u  = t + p * 256;
            int d  = u >> 4;
            int n4 = (u & 15) * 4;
            *reinterpret_cast<float4*>(&Ws[d][n4]) =
                *reinterpret_cast<const float4*>(&W[(size_t)(d0 + d) * 256 + n0 + n4]);
        }
        __syncthreads();
#pragma unroll
        for (int d = 0; d < 32; ++d) {
            float4 a4 = *reinterpret_cast<const float4*>(&As[d][mr]);
            float4 b4 = *reinterpret_cast<const float4*>(&Ws[d][nr]);
            float av[4] = {a4.x, a4.y, a4.z, a4.w};
            float bv[4] = {b4.x, b4.y, b4.z, b4.w};
#pragma unroll
            for (int i = 0; i < 4; ++i)
#pragma unroll
                for (int j = 0; j < 4; ++j)
                    acc[i][j] = fmaf(av[i], bv[j], acc[i][j]);
        }
        __syncthreads();
    }
#pragma unroll
    for (int i = 0; i < 4; ++i) {
        float4 o;
        o.x = e2x(acc[i][0]); o.y = e2x(acc[i][1]);
        o.z = e2x(acc[i][2]); o.w = e2x(acc[i][3]);
        *reinterpret_cast<float4*>(&C[(size_t)(m0 + mr + i) * 256 + n0 + nr]) = o;
    }
}

// ---------------------------------------------------------------------------
// Kernel 1b: Ekp[b][h2][k][2] = exp2(c * (keys[b] @ Wk)^T), h-pair interleaved.
// (round-2 version)
// ---------------------------------------------------------------------------
__global__ __launch_bounds__(256) void proj_k_kernel(const float* __restrict__ A,
                                                     const float* __restrict__ W,
                                                     float* __restrict__ CT) {
    __shared__ float smem[4352];   // As[32][68] + Ws[32][68]; reused as Cs[64][68]
    float (*As)[68] = reinterpret_cast<float(*)[68]>(smem);
    float (*Ws)[68] = reinterpret_cast<float(*)[68]>(smem + 2176);
    const int t  = threadIdx.x;
    const int m0 = blockIdx.x * 64;   // flat (b,k) row base
    const int n0 = blockIdx.y * 64;   // h base
    const int mr = (t & 15) * 4;
    const int nr = (t >> 4) * 4;

    float acc[4][4];
#pragma unroll
    for (int i = 0; i < 4; ++i)
#pragma unroll
        for (int j = 0; j < 4; ++j) acc[i][j] = 0.0f;

    for (int d0 = 0; d0 < 512; d0 += 32) {
#pragma unroll
        for (int p = 0; p < 2; ++p) {
            int u  = t + p * 256;
            int m  = u >> 3;
            int d4 = (u & 7) * 4;
            float4 a = *reinterpret_cast<const float4*>(&A[(size_t)(m0 + m) * 512 + d0 + d4]);
            As[d4 + 0][m] = a.x; As[d4 + 1][m] = a.y;
            As[d4 + 2][m] = a.z; As[d4 + 3][m] = a.w;
        }
#pragma unroll
        for (int p = 0; p < 2; ++p) {
            int u  = t + p * 256;
            int d  = u >> 4;
            int n4 = (u & 15) * 4;
            *reinterpret_cast<float4*>(&Ws[d][n4]) =
                *reinterpret_cast<const float4*>(&W[(size_t)(d0 + d) * 256 + n0 + n4]);
        }
        __syncthreads();
#pragma unroll
        for (int d = 0; d < 32; ++d) {
            float4 a4 = *reinterpret_cast<const float4*>(&As[d][mr]);
            float4 b4 = *reinterpret_cast<const float4*>(&Ws[d][nr]);
            float av[4] = {a4.x, a4.y, a4.z, a4.w};
            float bv[4] = {b4.x, b4.y, b4.z, b4.w};
#pragma unroll
            for (int i = 0; i < 4; ++i)
#pragma unroll
                for (int j = 0; j < 4; ++j)
                    acc[i][j] = fmaf(av[i], bv[j], acc[i][j]);
        }
        __syncthreads();   // also protects smem reuse as Cs below
    }
    // transpose in LDS: Cs[n(h)][m(k)]
    float (*Cs)[68] = reinterpret_cast<float(*)[68]>(smem);
#pragma unroll
    for (int i = 0; i < 4; ++i)
#pragma unroll
        for (int j = 0; j < 4; ++j)
            Cs[nr + j][mr + i] = acc[i][j];
    __syncthreads();

    const int b      = m0 >> 9;
    const int k0h    = (m0 & 511) >> 1;  // k0/2 in float4-pair units
    const int h2base = n0 >> 1;
    float4* out4 = reinterpret_cast<float4*>(CT);
#pragma unroll
    for (int p = 0; p < 4; ++p) {
        int u   = t + p * 256;       // 0..1023
        int h2r = u >> 5;            // 0..31
        int kk  = (u & 31) * 2;      // 0..62, step 2
        float4 o;
        o.x = e2x(Cs[2 * h2r    ][kk    ]);
        o.y = e2x(Cs[2 * h2r + 1][kk    ]);
        o.z = e2x(Cs[2 * h2r    ][kk + 1]);
        o.w = e2x(Cs[2 * h2r + 1][kk + 1]);
        out4[(size_t)b * 32768 + (size_t)(h2base + h2r) * 256 + k0h + (u & 31)] = o;
    }
}

// ---------------------------------------------------------------------------
// Kernel 2: scores + masked softmax -> attn[b][q][k]   (unchanged)
// ---------------------------------------------------------------------------
__global__ __launch_bounds__(256) void score_softmax_kernel(
        const float* __restrict__ Eq, const float* __restrict__ Ekp,
        const float* __restrict__ Wv, const int* __restrict__ valid_lens,
        float* __restrict__ attn) {
    __shared__ float redmA[4], redmB[4], redlA[4], redlB[4];

    const int t  = threadIdx.x;
    const int bq = blockIdx.x;        // 0..511
    const int b  = bq >> 5;
    const int q0 = (bq & 31) * 2;

    const float* eqA = Eq + (size_t)(b * 64 + q0) * 256;
    const float* eqB = eqA + 256;
    const float4* ek4 = reinterpret_cast<const float4*>(Ekp) + (size_t)b * 32768 + t;

    float accA0 = 0.f, accA1 = 0.f, accB0 = 0.f, accB1 = 0.f;
#pragma unroll 4
    for (int h2 = 0; h2 < 128; ++h2) {
        const float4 ek = ek4[h2 * 256];
        const float w0 = Wv[2 * h2];
        const float w1 = Wv[2 * h2 + 1];
        {
            const float e0 = eqA[2 * h2], e1 = eqA[2 * h2 + 1];
            float a00 = fmaf(e0, ek.x, 1.0f);
            float a10 = fmaf(e1, ek.y, 1.0f);
            float a01 = fmaf(e0, ek.z, 1.0f);
            float a11 = fmaf(e1, ek.w, 1.0f);
            float d0 = a00 * a10, d1 = a01 * a11;
            float n0 = fmaf(w1, a00, w0 * a10);
            float n1 = fmaf(w1, a01, w0 * a11);
            accA0 = fmaf(n0, __builtin_amdgcn_rcpf(d0), accA0);
            accA1 = fmaf(n1, __builtin_amdgcn_rcpf(d1), accA1);
        }
        {
            const float e0 = eqB[2 * h2], e1 = eqB[2 * h2 + 1];
            float a00 = fmaf(e0, ek.x, 1.0f);
            float a10 = fmaf(e1, ek.y, 1.0f);
            float a01 = fmaf(e0, ek.z, 1.0f);
            float a11 = fmaf(e1, ek.w, 1.0f);
            float d0 = a00 * a10, d1 = a01 * a11;
            float n0 = fmaf(w1, a00, w0 * a10);
            float n1 = fmaf(w1, a01, w0 * a11);
            accB0 = fmaf(n0, __builtin_amdgcn_rcpf(d0), accB0);
            accB1 = fmaf(n1, __builtin_amdgcn_rcpf(d1), accB1);
        }
    }
    float sA0 = -2.0f * accA0, sA1 = -2.0f * accA1;
    float sB0 = -2.0f * accB0, sB1 = -2.0f * accB1;
    const int vl = valid_lens[b];
    const int k0 = 2 * t;
    if (k0     >= vl) { sA0 = -1e6f; sB0 = -1e6f; }
    if (k0 + 1 >= vl) { sA1 = -1e6f; sB1 = -1e6f; }

    const int w = t >> 6;
    float mA = fmaxf(sA0, sA1);
    float mB = fmaxf(sB0, sB1);
#pragma unroll
    for (int off = 32; off > 0; off >>= 1) {
        mA = fmaxf(mA, __shfl_xor(mA, off));
        mB = fmaxf(mB, __shfl_xor(mB, off));
    }
    if ((t & 63) == 0) { redmA[w] = mA; redmB[w] = mB; }
    __syncthreads();
    mA = fmaxf(fmaxf(redmA[0], redmA[1]), fmaxf(redmA[2], redmA[3]));
    mB = fmaxf(fmaxf(redmB[0], redmB[1]), fmaxf(redmB[2], redmB[3]));

    float pA0 = __builtin_amdgcn_exp2f((sA0 - mA) * LOG2E);
    float pA1 = __builtin_amdgcn_exp2f((sA1 - mA) * LOG2E);
    float pB0 = __builtin_amdgcn_exp2f((sB0 - mB) * LOG2E);
    float pB1 = __builtin_amdgcn_exp2f((sB1 - mB) * LOG2E);
    float lA = pA0 + pA1, lB = pB0 + pB1;
#pragma unroll
    for (int off = 32; off > 0; off >>= 1) {
        lA += __shfl_xor(lA, off);
        lB += __shfl_xor(lB, off);
    }
    if ((t & 63) == 0) { redlA[w] = lA; redlB[w] = lB; }
    __syncthreads();
    lA = (redlA[0] + redlA[1]) + (redlA[2] + redlA[3]);
    lB = (redlB[0] + redlB[1]) + (redlB[2] + redlB[3]);
    const float invA = 1.0f / lA;
    const float invB = 1.0f / lB;

    float2* attn2 = reinterpret_cast<float2*>(attn);
    float2 oA; oA.x = pA0 * invA; oA.y = pA1 * invA;
    float2 oB; oB.x = pB0 * invB; oB.y = pB1 * invB;
    attn2[(size_t)(b * 64 + q0) * 256 + t]       = oA;
    attn2[(size_t)(b * 64 + q0 + 1) * 256 + t]   = oB;
}

// ---------------------------------------------------------------------------
// Kernel 3: out[b][q][v] = attn[b][q][:] @ values[b][:][v]
// Grid (4 v-chunks, 8 q-tiles, 16 b) = 512 blocks, 8 waves/CU.
// Thread = (q, float4 of v); full K=512; no k-split, no atomics.
// attn row chunks read from LDS via b128, broadcast across 32 lanes (free).
// ---------------------------------------------------------------------------
__global__ __launch_bounds__(256) void pv_kernel(const float* __restrict__ attn,
                                                 const float* __restrict__ values,
                                                 float* __restrict__ out) {
    __shared__ float attnS[8][512];    // 16 KB
    const int t   = threadIdx.x;
    const int b   = blockIdx.z;
    const int q0  = blockIdx.y * 8;
    const int v4b = blockIdx.x * 32;   // float4 col base (128 floats of v)

    const float4* attn4 = reinterpret_cast<const float4*>(attn) + (size_t)(b * 64 + q0) * 128;
#pragma unroll
    for (int p = 0; p < 4; ++p) {
        int u  = t + p * 256;          // 0..1023
        int qr = u >> 7;               // 0..7
        int c4 = u & 127;              // 0..127
        *reinterpret_cast<float4*>(&attnS[qr][c4 * 4]) = attn4[qr * 128 + c4];
    }
    __syncthreads();

    const int q  = t >> 5;             // 0..7
    const int v4 = v4b + (t & 31);     // float4 col index (0..127)
    const float4* val4 = reinterpret_cast<const float4*>(values) + (size_t)b * 512 * 128 + v4;
    const float* arow = attnS[q];

    float ax = 0.f, ay = 0.f, az = 0.f, aw = 0.f;
#pragma unroll 2
    for (int kk = 0; kk < 512; kk += 4) {
        float4 a  = *reinterpret_cast<const float4*>(&arow[kk]);
        float4 v0 = val4[(size_t)(kk + 0) * 128];
        float4 v1 = val4[(size_t)(kk + 1) * 128];
        float4 v2 = val4[(size_t)(kk + 2) * 128];
        float4 v3 = val4[(size_t)(kk + 3) * 128];
        ax = fmaf(a.x, v0.x, ax); ay = fmaf(a.x, v0.y, ay);
        az = fmaf(a.x, v0.z, az); aw = fmaf(a.x, v0.w, aw);
        ax = fmaf(a.y, v1.x, ax); ay = fmaf(a.y, v1.y, ay);
        az = fmaf(a.y, v1.z, az); aw = fmaf(a.y, v1.w, aw);
        ax = fmaf(a.z, v2.x, ax); ay = fmaf(a.z, v2.y, ay);
        az = fmaf(a.z, v2.z, az); aw = fmaf(a.z, v2.w, aw);
        ax = fmaf(a.w, v3.x, ax); ay = fmaf(a.w, v3.y, ay);
        az = fmaf(a.w, v3.z, az); aw = fmaf(a.w, v3.w, aw);
    }
    float4 o; o.x = ax; o.y = ay; o.z = az; o.w = aw;
    reinterpret_cast<float4*>(out)[(size_t)(b * 64 + q0 + q) * 128 + v4] = o;
}

// ---------------------------------------------------------------------------
extern "C" void kernel_launch(void* const* d_in, const int* in_sizes, int n_in,
                              void* d_out, int out_size, void* d_ws, size_t ws_size,
                              hipStream_t stream) {
    (void)in_sizes; (void)n_in; (void)out_size; (void)ws_size;
    const float* queries    = (const float*)d_in[0];   // [16,64,512]
    const float* keys       = (const float*)d_in[1];   // [16,512,512]
    const float* values     = (const float*)d_in[2];   // [16,512,512]
    const int*   valid_lens = (const int*)d_in[3];     // [16]
    const float* Wq         = (const float*)d_in[4];   // [512,256]
    const float* Wk         = (const float*)d_in[5];   // [512,256]
    const float* Wv         = (const float*)d_in[6];   // [256]
    float* out = (float*)d_out;                        // [16,64,512]

    float* ws   = (float*)d_ws;
    float* Eq   = ws;                        // [1024][256]              1 MB
    float* Ekp  = ws + 262144;               // [16][128][512][2]        8 MB
    float* attn = ws + 262144 + 2097152;     // [16][64][512]            2 MB

    hipLaunchKernelGGL(proj_q_kernel, dim3(16, 4), dim3(256), 0, stream, queries, Wq, Eq);
    hipLaunchKernelGGL(proj_k_kernel, dim3(128, 4), dim3(256), 0, stream, keys, Wk, Ekp);
    hipLaunchKernelGGL(score_softmax_kernel, dim3(512), dim3(256), 0, stream,
                       Eq, Ekp, Wv, valid_lens, attn);
    hipLaunchKernelGGL(pv_kernel, dim3(4, 8, 16), dim3(256), 0, stream, attn, values, out);
}

// Round 5
// 179.425 us; speedup vs baseline: 1.2311x; 1.0519x over previous
//
#include <hip/hip_runtime.h>

// Problem dims: B=16, Q=64, K=512, DQ=DK=DV=512, H=256
#define LOG2E 1.4426950408889634f
#define TWO_LOG2E 2.8853900817779268f

__device__ __forceinline__ float e2x(float v) {
    // exp2(2*log2(e)*v) == e^{2v}
    return __builtin_amdgcn_exp2f(v * TWO_LOG2E);
}

// ---------------------------------------------------------------------------
// Kernel 1 (fused): projections for BOTH queries and keys.
//   rows 0..15   (x64): Eq[1024][256] = exp2(c * queries @ Wq)
//   rows 16..143 (x64): Ekp[b][h2][k][2] = exp2(c * (keys @ Wk)^T), pair layout
// Grid (144, 4) = 576 blocks; 64x64 tile, 4x4 micro-tile, K-chunk 32.
// ---------------------------------------------------------------------------
__global__ __launch_bounds__(256) void proj_kernel(const float* __restrict__ queries,
                                                   const float* __restrict__ keys,
                                                   const float* __restrict__ Wq,
                                                   const float* __restrict__ Wk,
                                                   float* __restrict__ Eq,
                                                   float* __restrict__ Ekp) {
    __shared__ float smem[4352];   // As[32][68] + Ws[32][68]; reused as Cs[64][68]
    float (*As)[68] = reinterpret_cast<float(*)[68]>(smem);
    float (*Ws)[68] = reinterpret_cast<float(*)[68]>(smem + 2176);
    const int t    = threadIdx.x;
    const int rt   = blockIdx.x;           // 0..143
    const bool isQ = rt < 16;
    const float* A = isQ ? queries : keys;
    const float* W = isQ ? Wq : Wk;
    const int m0   = (isQ ? rt : rt - 16) * 64;   // local row base in A
    const int n0   = blockIdx.y * 64;
    const int mr   = (t & 15) * 4;
    const int nr   = (t >> 4) * 4;

    float acc[4][4];
#pragma unroll
    for (int i = 0; i < 4; ++i)
#pragma unroll
        for (int j = 0; j < 4; ++j) acc[i][j] = 0.0f;

    for (int d0 = 0; d0 < 512; d0 += 32) {
#pragma unroll
        for (int p = 0; p < 2; ++p) {
            int u  = t + p * 256;
            int m  = u >> 3;
            int d4 = (u & 7) * 4;
            float4 a = *reinterpret_cast<const float4*>(&A[(size_t)(m0 + m) * 512 + d0 + d4]);
            As[d4 + 0][m] = a.x; As[d4 + 1][m] = a.y;
            As[d4 + 2][m] = a.z; As[d4 + 3][m] = a.w;
        }
#pragma unroll
        for (int p = 0; p < 2; ++p) {
            int u  = t + p * 256;
            int d  = u >> 4;
            int n4 = (u & 15) * 4;
            *reinterpret_cast<float4*>(&Ws[d][n4]) =
                *reinterpret_cast<const float4*>(&W[(size_t)(d0 + d) * 256 + n0 + n4]);
        }
        __syncthreads();
#pragma unroll
        for (int d = 0; d < 32; ++d) {
            float4 a4 = *reinterpret_cast<const float4*>(&As[d][mr]);
            float4 b4 = *reinterpret_cast<const float4*>(&Ws[d][nr]);
            float av[4] = {a4.x, a4.y, a4.z, a4.w};
            float bv[4] = {b4.x, b4.y, b4.z, b4.w};
#pragma unroll
            for (int i = 0; i < 4; ++i)
#pragma unroll
                for (int j = 0; j < 4; ++j)
                    acc[i][j] = fmaf(av[i], bv[j], acc[i][j]);
        }
        __syncthreads();
    }

    if (isQ) {
        // Eq epilogue: direct store
#pragma unroll
        for (int i = 0; i < 4; ++i) {
            float4 o;
            o.x = e2x(acc[i][0]); o.y = e2x(acc[i][1]);
            o.z = e2x(acc[i][2]); o.w = e2x(acc[i][3]);
            *reinterpret_cast<float4*>(&Eq[(size_t)(m0 + mr + i) * 256 + n0 + nr]) = o;
        }
    } else {
        // transpose in LDS: Cs[n(h)][m(k)], then pair-interleaved store
        float (*Cs)[68] = reinterpret_cast<float(*)[68]>(smem);
#pragma unroll
        for (int i = 0; i < 4; ++i)
#pragma unroll
            for (int j = 0; j < 4; ++j)
                Cs[nr + j][mr + i] = acc[i][j];
        __syncthreads();

        const int b      = m0 >> 9;
        const int k0h    = (m0 & 511) >> 1;
        const int h2base = n0 >> 1;
        float4* out4 = reinterpret_cast<float4*>(Ekp);
#pragma unroll
        for (int p = 0; p < 4; ++p) {
            int u   = t + p * 256;       // 0..1023
            int h2r = u >> 5;            // 0..31
            int kk  = (u & 31) * 2;      // 0..62, step 2
            float4 o;
            o.x = e2x(Cs[2 * h2r    ][kk    ]);
            o.y = e2x(Cs[2 * h2r + 1][kk    ]);
            o.z = e2x(Cs[2 * h2r    ][kk + 1]);
            o.w = e2x(Cs[2 * h2r + 1][kk + 1]);
            out4[(size_t)b * 32768 + (size_t)(h2base + h2r) * 256 + k0h + (u & 31)] = o;
        }
    }
}

// ---------------------------------------------------------------------------
// Kernel 2: scores + masked softmax -> attn[b][q][k]   (unchanged)
// ---------------------------------------------------------------------------
__global__ __launch_bounds__(256) void score_softmax_kernel(
        const float* __restrict__ Eq, const float* __restrict__ Ekp,
        const float* __restrict__ Wv, const int* __restrict__ valid_lens,
        float* __restrict__ attn) {
    __shared__ float redmA[4], redmB[4], redlA[4], redlB[4];

    const int t  = threadIdx.x;
    const int bq = blockIdx.x;        // 0..511
    const int b  = bq >> 5;
    const int q0 = (bq & 31) * 2;

    const float* eqA = Eq + (size_t)(b * 64 + q0) * 256;
    const float* eqB = eqA + 256;
    const float4* ek4 = reinterpret_cast<const float4*>(Ekp) + (size_t)b * 32768 + t;

    float accA0 = 0.f, accA1 = 0.f, accB0 = 0.f, accB1 = 0.f;
#pragma unroll 4
    for (int h2 = 0; h2 < 128; ++h2) {
        const float4 ek = ek4[h2 * 256];
        const float w0 = Wv[2 * h2];
        const float w1 = Wv[2 * h2 + 1];
        {
            const float e0 = eqA[2 * h2], e1 = eqA[2 * h2 + 1];
            float a00 = fmaf(e0, ek.x, 1.0f);
            float a10 = fmaf(e1, ek.y, 1.0f);
            float a01 = fmaf(e0, ek.z, 1.0f);
            float a11 = fmaf(e1, ek.w, 1.0f);
            float d0 = a00 * a10, d1 = a01 * a11;
            float n0 = fmaf(w1, a00, w0 * a10);
            float n1 = fmaf(w1, a01, w0 * a11);
            accA0 = fmaf(n0, __builtin_amdgcn_rcpf(d0), accA0);
            accA1 = fmaf(n1, __builtin_amdgcn_rcpf(d1), accA1);
        }
        {
            const float e0 = eqB[2 * h2], e1 = eqB[2 * h2 + 1];
            float a00 = fmaf(e0, ek.x, 1.0f);
            float a10 = fmaf(e1, ek.y, 1.0f);
            float a01 = fmaf(e0, ek.z, 1.0f);
            float a11 = fmaf(e1, ek.w, 1.0f);
            float d0 = a00 * a10, d1 = a01 * a11;
            float n0 = fmaf(w1, a00, w0 * a10);
            float n1 = fmaf(w1, a01, w0 * a11);
            accB0 = fmaf(n0, __builtin_amdgcn_rcpf(d0), accB0);
            accB1 = fmaf(n1, __builtin_amdgcn_rcpf(d1), accB1);
        }
    }
    float sA0 = -2.0f * accA0, sA1 = -2.0f * accA1;
    float sB0 = -2.0f * accB0, sB1 = -2.0f * accB1;
    const int vl = valid_lens[b];
    const int k0 = 2 * t;
    if (k0     >= vl) { sA0 = -1e6f; sB0 = -1e6f; }
    if (k0 + 1 >= vl) { sA1 = -1e6f; sB1 = -1e6f; }

    const int w = t >> 6;
    float mA = fmaxf(sA0, sA1);
    float mB = fmaxf(sB0, sB1);
#pragma unroll
    for (int off = 32; off > 0; off >>= 1) {
        mA = fmaxf(mA, __shfl_xor(mA, off));
        mB = fmaxf(mB, __shfl_xor(mB, off));
    }
    if ((t & 63) == 0) { redmA[w] = mA; redmB[w] = mB; }
    __syncthreads();
    mA = fmaxf(fmaxf(redmA[0], redmA[1]), fmaxf(redmA[2], redmA[3]));
    mB = fmaxf(fmaxf(redmB[0], redmB[1]), fmaxf(redmB[2], redmB[3]));

    float pA0 = __builtin_amdgcn_exp2f((sA0 - mA) * LOG2E);
    float pA1 = __builtin_amdgcn_exp2f((sA1 - mA) * LOG2E);
    float pB0 = __builtin_amdgcn_exp2f((sB0 - mB) * LOG2E);
    float pB1 = __builtin_amdgcn_exp2f((sB1 - mB) * LOG2E);
    float lA = pA0 + pA1, lB = pB0 + pB1;
#pragma unroll
    for (int off = 32; off > 0; off >>= 1) {
        lA += __shfl_xor(lA, off);
        lB += __shfl_xor(lB, off);
    }
    if ((t & 63) == 0) { redlA[w] = lA; redlB[w] = lB; }
    __syncthreads();
    lA = (redlA[0] + redlA[1]) + (redlA[2] + redlA[3]);
    lB = (redlB[0] + redlB[1]) + (redlB[2] + redlB[3]);
    const float invA = 1.0f / lA;
    const float invB = 1.0f / lB;

    float2* attn2 = reinterpret_cast<float2*>(attn);
    float2 oA; oA.x = pA0 * invA; oA.y = pA1 * invA;
    float2 oB; oB.x = pB0 * invB; oB.y = pB1 * invB;
    attn2[(size_t)(b * 64 + q0) * 256 + t]       = oA;
    attn2[(size_t)(b * 64 + q0 + 1) * 256 + t]   = oB;
}

// ---------------------------------------------------------------------------
// Kernel 3: out[b][q][v] = attn[b][q][:] @ values[b][:][v]
// Grid (4 v-chunks, 16 q-tiles, 16 b) = 1024 blocks (4/CU, 16 waves/CU).
// 256 thr = 2 k-halves x 4 q x 32 v4; manual 4-load prefetch pipeline;
// k-halves combined through LDS (no atomics).
// ---------------------------------------------------------------------------
__global__ __launch_bounds__(256) void pv_kernel(const float* __restrict__ attn,
                                                 const float* __restrict__ values,
                                                 float* __restrict__ out) {
    __shared__ float attnS[4][512];    // 8 KB; reused as reduction buffer
    const int t   = threadIdx.x;
    const int b   = blockIdx.z;
    const int q0  = blockIdx.y * 4;
    const int v4b = blockIdx.x * 32;   // float4 col base (128 floats of v)

    const float4* attn4 = reinterpret_cast<const float4*>(attn) + (size_t)(b * 64 + q0) * 128;
#pragma unroll
    for (int p = 0; p < 2; ++p) {
        int u  = t + p * 256;          // 0..511
        int qr = u >> 7;               // 0..3
        int c4 = u & 127;              // 0..127
        *reinterpret_cast<float4*>(&attnS[qr][c4 * 4]) = attn4[qr * 128 + c4];
    }
    __syncthreads();

    const int kh = t >> 7;             // k-half: 0 or 1
    const int q  = (t >> 5) & 3;       // 0..3
    const int v4 = v4b + (t & 31);     // float4 col index (0..127)
    const float* arow = &attnS[q][kh * 256];
    const float4* vp = reinterpret_cast<const float4*>(values)
                     + ((size_t)b * 512 + (size_t)kh * 256) * 128 + v4;

    float ax = 0.f, ay = 0.f, az = 0.f, aw = 0.f;
    float4 n0 = vp[0], n1 = vp[128], n2 = vp[256], n3 = vp[384];
#pragma unroll 2
    for (int kk = 0; kk < 256; kk += 4) {
        float4 c0 = n0, c1 = n1, c2 = n2, c3 = n3;
        vp += 512;
        if (kk + 4 < 256) { n0 = vp[0]; n1 = vp[128]; n2 = vp[256]; n3 = vp[384]; }
        float4 a = *reinterpret_cast<const float4*>(&arow[kk]);
        ax = fmaf(a.x, c0.x, ax); ay = fmaf(a.x, c0.y, ay);
        az = fmaf(a.x, c0.z, az); aw = fmaf(a.x, c0.w, aw);
        ax = fmaf(a.y, c1.x, ax); ay = fmaf(a.y, c1.y, ay);
        az = fmaf(a.y, c1.z, az); aw = fmaf(a.y, c1.w, aw);
        ax = fmaf(a.z, c2.x, ax); ay = fmaf(a.z, c2.y, ay);
        az = fmaf(a.z, c2.z, az); aw = fmaf(a.z, c2.w, aw);
        ax = fmaf(a.w, c3.x, ax); ay = fmaf(a.w, c3.y, ay);
        az = fmaf(a.w, c3.z, az); aw = fmaf(a.w, c3.w, aw);
    }

    __syncthreads();                   // attnS reads done; reuse as reduction buf
    float* red = &attnS[0][0];         // 128 threads x 4 floats = 2 KB
    if (kh == 1) {
        float4 o; o.x = ax; o.y = ay; o.z = az; o.w = aw;
        *reinterpret_cast<float4*>(&red[(t - 128) * 4]) = o;
    }
    __syncthreads();
    if (kh == 0) {
        float4 o = *reinterpret_cast<const float4*>(&red[t * 4]);
        o.x += ax; o.y += ay; o.z += az; o.w += aw;
        reinterpret_cast<float4*>(out)[(size_t)(b * 64 + q0 + q) * 128 + v4] = o;
    }
}

// ---------------------------------------------------------------------------
extern "C" void kernel_launch(void* const* d_in, const int* in_sizes, int n_in,
                              void* d_out, int out_size, void* d_ws, size_t ws_size,
                              hipStream_t stream) {
    (void)in_sizes; (void)n_in; (void)out_size; (void)ws_size;
    const float* queries    = (const float*)d_in[0];   // [16,64,512]
    const float* keys       = (const float*)d_in[1];   // [16,512,512]
    const float* values     = (const float*)d_in[2];   // [16,512,512]
    const int*   valid_lens = (const int*)d_in[3];     // [16]
    const float* Wq         = (const float*)d_in[4];   // [512,256]
    const float* Wk         = (const float*)d_in[5];   // [512,256]
    const float* Wv         = (const float*)d_in[6];   // [256]
    float* out = (float*)d_out;                        // [16,64,512]

    float* ws   = (float*)d_ws;
    float* Eq   = ws;                        // [1024][256]              1 MB
    float* Ekp  = ws + 262144;               // [16][128][512][2]        8 MB
    float* attn = ws + 262144 + 2097152;     // [16][64][512]            2 MB

    hipLaunchKernelGGL(proj_kernel, dim3(144, 4), dim3(256), 0, stream,
                       queries, keys, Wq, Wk, Eq, Ekp);
    hipLaunchKernelGGL(score_softmax_kernel, dim3(512), dim3(256), 0, stream,
                       Eq, Ekp, Wv, valid_lens, attn);
    hipLaunchKernelGGL(pv_kernel, dim3(4, 16, 16), dim3(256), 0, stream, attn, values, out);
}

// Round 6
// 166.178 us; speedup vs baseline: 1.3292x; 1.0797x over previous
//
#include <hip/hip_runtime.h>

// Problem dims: B=16, Q=64, K=512, DQ=DK=DV=512, H=256
#define LOG2E 1.4426950408889634f
#define TWO_LOG2E 2.8853900817779268f

typedef __attribute__((ext_vector_type(8))) short short8;   // bf16x8 MFMA frag
typedef __attribute__((ext_vector_type(4))) float f32x4;    // MFMA acc

__device__ __forceinline__ float e2x(float v) {
    // exp2(2*log2(e)*v) == e^{2v}
    return __builtin_amdgcn_exp2f(v * TWO_LOG2E);
}

// Exact fp32 -> (hi,lo) bf16 split, packed: hi = top16(f) (truncation, exact),
// lo = f - hi (exactly representable in bf16: <=8 significand bits).
__device__ __forceinline__ void split2(float x, float y, unsigned& hi, unsigned& lo) {
    unsigned ux = __float_as_uint(x), uy = __float_as_uint(y);
    float hx = __uint_as_float(ux & 0xffff0000u);
    float hy = __uint_as_float(uy & 0xffff0000u);
    unsigned lx = __float_as_uint(x - hx), ly = __float_as_uint(y - hy);
    hi = (ux >> 16) | (uy & 0xffff0000u);
    lo = (lx >> 16) | (ly & 0xffff0000u);
}

// ---------------------------------------------------------------------------
// Kernel 0: W2T[n][k'] split/transposed weights, chunk-interleaved:
// per 32-k chunk c: [c*96 +0..31]=Whi, [+32..63]=Whi, [+64..95]=Wlo.
// Matches A-chunk layout [Ahi|Alo|Ahi] -> 3-term split product.
// grid (8 k-tiles, 4 n-tiles, 2 matrices{Wq,Wk}), 256 thr.
// ---------------------------------------------------------------------------
__global__ __launch_bounds__(256) void wprep_kernel(const float* __restrict__ Wq,
                                                    const float* __restrict__ Wk,
                                                    ushort* __restrict__ Wq2T,
                                                    ushort* __restrict__ Wk2T) {
    __shared__ float T[64][65];
    const float* W  = blockIdx.z ? Wk : Wq;
    ushort* W2T     = blockIdx.z ? Wk2T : Wq2T;
    const int t  = threadIdx.x;
    const int k0 = blockIdx.x * 64;
    const int n0 = blockIdx.y * 64;
#pragma unroll
    for (int p = 0; p < 4; ++p) {
        int u  = t + p * 256;          // 0..1023
        int kk = u >> 4;               // 0..63
        int nf = (u & 15) * 4;
        float4 w = *reinterpret_cast<const float4*>(&W[(size_t)(k0 + kk) * 256 + n0 + nf]);
        T[nf + 0][kk] = w.x; T[nf + 1][kk] = w.y;
        T[nf + 2][kk] = w.z; T[nf + 3][kk] = w.w;
    }
    __syncthreads();
#pragma unroll
    for (int p = 0; p < 4; ++p) {
        int u  = t + p * 256;
        int n  = u >> 4;               // 0..63
        int kf = (u & 15) * 4;         // 0..60
        float a = T[n][kf], b = T[n][kf + 1], c = T[n][kf + 2], d = T[n][kf + 3];
        unsigned h01, l01, h23, l23;
        split2(a, b, h01, l01);
        split2(c, d, h23, l23);
        int kg = k0 + kf;
        ushort* row = W2T + (size_t)(n0 + n) * 1536 + (kg >> 5) * 96 + (kg & 31);
        uint2 hi; hi.x = h01; hi.y = h23;
        uint2 lo; lo.x = l01; lo.y = l23;
        *reinterpret_cast<uint2*>(row)      = hi;   // seg0: hi
        *reinterpret_cast<uint2*>(row + 32) = hi;   // seg1: hi
        *reinterpret_cast<uint2*>(row + 64) = lo;   // seg2: lo
    }
}

// ---------------------------------------------------------------------------
// Kernel 1: fused MFMA projection (bf16 3-term split = fp32-accurate).
//   m-tiles 0..7   : Eq[1024][256] = exp2(c * queries @ Wq)
//   m-tiles 8..71  : Ekp[b][h2][k][2] = exp2(c * (keys @ Wk)^T), pair layout
// Block 128m x 64n, 4 waves (2x2), wave-tile 64x32 (4x2 frags of 16x16x32).
// K-loop: 16 chunks; per chunk A fp32->split in regs->LDS [hi|lo|hi],
// B streamed from W2T via global_load_lds (16B). Grid (72,4) = 288 blocks.
// ---------------------------------------------------------------------------
__global__ __launch_bounds__(256) void mfma_proj_kernel(const float* __restrict__ queries,
                                                        const float* __restrict__ keys,
                                                        const ushort* __restrict__ Wq2T,
                                                        const ushort* __restrict__ Wk2T,
                                                        float* __restrict__ Eq,
                                                        float* __restrict__ Ekp) {
    __shared__ float smemf[9216];            // 36864 B: Ah(24576) + Ws(12288); reused as Cs
    ushort* Ah = reinterpret_cast<ushort*>(smemf);           // [128 m][96 k']
    ushort* Ws = reinterpret_cast<ushort*>(smemf) + 12288;   // [64 n][96 k']

    const int t    = threadIdx.x;
    const int mt   = blockIdx.x;             // 0..71
    const int Nb   = blockIdx.y * 64;
    const bool isQ = mt < 8;
    const int Mb   = mt * 128;
    const float4* Asrc4 = reinterpret_cast<const float4*>(isQ ? queries : keys)
                        + (size_t)(isQ ? Mb : Mb - 1024) * 128;
    const ushort* W2T = isQ ? Wq2T : Wk2T;

    const int ln15 = t & 15;
    const int q    = (t >> 4) & 3;
    const int w    = t >> 6;
    const int wm   = (w >> 1) * 64;          // wave m-offset
    const int wn   = (w & 1) * 32;           // wave n-offset

    // global_load_lds lane mapping for B staging (3 instrs of 4096 B)
    int bn[3], brem[3];
#pragma unroll
    for (int i = 0; i < 3; ++i) {
        int o   = i * 4096 + (t >> 6) * 1024 + (t & 63) * 16;  // linear byte in Ws
        bn[i]   = o / 192;                   // n row (192 B per row)
        brem[i] = o - bn[i] * 192;           // byte within row
    }
    const char* gB[3];
#pragma unroll
    for (int i = 0; i < 3; ++i)
        gB[i] = reinterpret_cast<const char*>(W2T) + (size_t)(Nb + bn[i]) * 3072 + brem[i];

    f32x4 acc[4][2];
#pragma unroll
    for (int fm = 0; fm < 4; ++fm)
#pragma unroll
        for (int fn = 0; fn < 2; ++fn) acc[fm][fn] = (f32x4)0.0f;

    for (int c = 0; c < 16; ++c) {
        __syncthreads();                     // previous chunk's LDS reads done
        // --- stage A: load fp32, split, write [hi|lo|hi] ---
#pragma unroll
        for (int p = 0; p < 4; ++p) {
            int u  = t + p * 256;            // 0..1023
            int m  = u >> 3;                 // 0..127
            int kf = (u & 7) * 4;            // 0..28
            float4 a = Asrc4[(size_t)m * 128 + c * 8 + (u & 7)];
            unsigned h01, l01, h23, l23;
            split2(a.x, a.y, h01, l01);
            split2(a.z, a.w, h23, l23);
            uint2 hi; hi.x = h01; hi.y = h23;
            uint2 lo; lo.x = l01; lo.y = l23;
            ushort* row = Ah + m * 96 + kf;
            *reinterpret_cast<uint2*>(row)      = hi;
            *reinterpret_cast<uint2*>(row + 32) = lo;
            *reinterpret_cast<uint2*>(row + 64) = hi;
        }
        // --- stage B: direct global->LDS, 3 x 16B/lane ---
#pragma unroll
        for (int i = 0; i < 3; ++i) {
            __builtin_amdgcn_global_load_lds(
                reinterpret_cast<const unsigned int*>(gB[i]),
                reinterpret_cast<unsigned int*>(
                    reinterpret_cast<char*>(Ws) + i * 4096 + (t >> 6) * 1024),
                16, 0, 0);
            gB[i] += 192;
        }
        __syncthreads();                     // drains vmcnt + lgkm
        // --- compute: 3 split-terms x (4m x 2n) MFMAs ---
#pragma unroll
        for (int s = 0; s < 3; ++s) {
            short8 af[4], bf[2];
#pragma unroll
            for (int fm = 0; fm < 4; ++fm)
                af[fm] = *reinterpret_cast<const short8*>(
                    Ah + (wm + fm * 16 + ln15) * 96 + s * 32 + q * 8);
#pragma unroll
            for (int fn = 0; fn < 2; ++fn)
                bf[fn] = *reinterpret_cast<const short8*>(
                    Ws + (wn + fn * 16 + ln15) * 96 + s * 32 + q * 8);
#pragma unroll
            for (int fm = 0; fm < 4; ++fm)
#pragma unroll
                for (int fn = 0; fn < 2; ++fn)
                    acc[fm][fn] = __builtin_amdgcn_mfma_f32_16x16x32_bf16(
                        af[fm], bf[fn], acc[fm][fn], 0, 0, 0);
        }
    }

    // C/D layout: col = lane&15, row = quad*4 + reg  (m89/m91-verified)
    if (isQ) {
#pragma unroll
        for (int fm = 0; fm < 4; ++fm)
#pragma unroll
            for (int fn = 0; fn < 2; ++fn)
#pragma unroll
                for (int r = 0; r < 4; ++r) {
                    int row = Mb + wm + fm * 16 + q * 4 + r;
                    int col = Nb + wn + fn * 16 + ln15;
                    Eq[(size_t)row * 256 + col] = e2x(acc[fm][fn][r]);
                }
    } else {
        __syncthreads();                     // all waves done with Ah/Ws
        float (*Cs)[131] = reinterpret_cast<float(*)[131]>(smemf);  // [n 64][m 128]
#pragma unroll
        for (int fm = 0; fm < 4; ++fm)
#pragma unroll
            for (int fn = 0; fn < 2; ++fn)
#pragma unroll
                for (int r = 0; r < 4; ++r) {
                    int m_l = wm + fm * 16 + q * 4 + r;
                    int n_l = wn + fn * 16 + ln15;
                    Cs[n_l][m_l] = acc[fm][fn][r];
                }
        __syncthreads();
        const int rk     = Mb - 1024;        // flat (b,k) base
        const int b      = rk >> 9;
        const int k0h    = (rk & 511) >> 1;
        const int h2base = Nb >> 1;
        float4* out4 = reinterpret_cast<float4*>(Ekp);
#pragma unroll
        for (int p = 0; p < 8; ++p) {
            int u   = t + p * 256;           // 0..2047
            int h2r = u >> 6;                // 0..31
            int kp  = u & 63;                // k-pair 0..63
            int kk  = kp * 2;
            float4 o;
            o.x = e2x(Cs[2 * h2r    ][kk    ]);
            o.y = e2x(Cs[2 * h2r + 1][kk    ]);
            o.z = e2x(Cs[2 * h2r    ][kk + 1]);
            o.w = e2x(Cs[2 * h2r + 1][kk + 1]);
            out4[(size_t)b * 32768 + (size_t)(h2base + h2r) * 256 + k0h + kp] = o;
        }
    }
}

// ---------------------------------------------------------------------------
// Kernel 2: scores + masked softmax -> attn[b][q][k]   (unchanged)
// ---------------------------------------------------------------------------
__global__ __launch_bounds__(256) void score_softmax_kernel(
        const float* __restrict__ Eq, const float* __restrict__ Ekp,
        const float* __restrict__ Wv, const int* __restrict__ valid_lens,
        float* __restrict__ attn) {
    __shared__ float redmA[4], redmB[4], redlA[4], redlB[4];

    const int t  = threadIdx.x;
    const int bq = blockIdx.x;        // 0..511
    const int b  = bq >> 5;
    const int q0 = (bq & 31) * 2;

    const float* eqA = Eq + (size_t)(b * 64 + q0) * 256;
    const float* eqB = eqA + 256;
    const float4* ek4 = reinterpret_cast<const float4*>(Ekp) + (size_t)b * 32768 + t;

    float accA0 = 0.f, accA1 = 0.f, accB0 = 0.f, accB1 = 0.f;
#pragma unroll 4
    for (int h2 = 0; h2 < 128; ++h2) {
        const float4 ek = ek4[h2 * 256];
        const float w0 = Wv[2 * h2];
        const float w1 = Wv[2 * h2 + 1];
        {
            const float e0 = eqA[2 * h2], e1 = eqA[2 * h2 + 1];
            float a00 = fmaf(e0, ek.x, 1.0f);
            float a10 = fmaf(e1, ek.y, 1.0f);
            float a01 = fmaf(e0, ek.z, 1.0f);
            float a11 = fmaf(e1, ek.w, 1.0f);
            float d0 = a00 * a10, d1 = a01 * a11;
            float n0 = fmaf(w1, a00, w0 * a10);
            float n1 = fmaf(w1, a01, w0 * a11);
            accA0 = fmaf(n0, __builtin_amdgcn_rcpf(d0), accA0);
            accA1 = fmaf(n1, __builtin_amdgcn_rcpf(d1), accA1);
        }
        {
            const float e0 = eqB[2 * h2], e1 = eqB[2 * h2 + 1];
            float a00 = fmaf(e0, ek.x, 1.0f);
            float a10 = fmaf(e1, ek.y, 1.0f);
            float a01 = fmaf(e0, ek.z, 1.0f);
            float a11 = fmaf(e1, ek.w, 1.0f);
            float d0 = a00 * a10, d1 = a01 * a11;
            float n0 = fmaf(w1, a00, w0 * a10);
            float n1 = fmaf(w1, a01, w0 * a11);
            accB0 = fmaf(n0, __builtin_amdgcn_rcpf(d0), accB0);
            accB1 = fmaf(n1, __builtin_amdgcn_rcpf(d1), accB1);
        }
    }
    float sA0 = -2.0f * accA0, sA1 = -2.0f * accA1;
    float sB0 = -2.0f * accB0, sB1 = -2.0f * accB1;
    const int vl = valid_lens[b];
    const int k0 = 2 * t;
    if (k0     >= vl) { sA0 = -1e6f; sB0 = -1e6f; }
    if (k0 + 1 >= vl) { sA1 = -1e6f; sB1 = -1e6f; }

    const int w = t >> 6;
    float mA = fmaxf(sA0, sA1);
    float mB = fmaxf(sB0, sB1);
#pragma unroll
    for (int off = 32; off > 0; off >>= 1) {
        mA = fmaxf(mA, __shfl_xor(mA, off));
        mB = fmaxf(mB, __shfl_xor(mB, off));
    }
    if ((t & 63) == 0) { redmA[w] = mA; redmB[w] = mB; }
    __syncthreads();
    mA = fmaxf(fmaxf(redmA[0], redmA[1]), fmaxf(redmA[2], redmA[3]));
    mB = fmaxf(fmaxf(redmB[0], redmB[1]), fmaxf(redmB[2], redmB[3]));

    float pA0 = __builtin_amdgcn_exp2f((sA0 - mA) * LOG2E);
    float pA1 = __builtin_amdgcn_exp2f((sA1 - mA) * LOG2E);
    float pB0 = __builtin_amdgcn_exp2f((sB0 - mB) * LOG2E);
    float pB1 = __builtin_amdgcn_exp2f((sB1 - mB) * LOG2E);
    float lA = pA0 + pA1, lB = pB0 + pB1;
#pragma unroll
    for (int off = 32; off > 0; off >>= 1) {
        lA += __shfl_xor(lA, off);
        lB += __shfl_xor(lB, off);
    }
    if ((t & 63) == 0) { redlA[w] = lA; redlB[w] = lB; }
    __syncthreads();
    lA = (redlA[0] + redlA[1]) + (redlA[2] + redlA[3]);
    lB = (redlB[0] + redlB[1]) + (redlB[2] + redlB[3]);
    const float invA = 1.0f / lA;
    const float invB = 1.0f / lB;

    float2* attn2 = reinterpret_cast<float2*>(attn);
    float2 oA; oA.x = pA0 * invA; oA.y = pA1 * invA;
    float2 oB; oB.x = pB0 * invB; oB.y = pB1 * invB;
    attn2[(size_t)(b * 64 + q0) * 256 + t]       = oA;
    attn2[(size_t)(b * 64 + q0 + 1) * 256 + t]   = oB;
}

// ---------------------------------------------------------------------------
// Kernel 3: out[b][q][v] = attn[b][q][:] @ values[b][:][v]   (unchanged)
// ---------------------------------------------------------------------------
__global__ __launch_bounds__(256) void pv_kernel(const float* __restrict__ attn,
                                                 const float* __restrict__ values,
                                                 float* __restrict__ out) {
    __shared__ float attnS[4][512];    // 8 KB; reused as reduction buffer
    const int t   = threadIdx.x;
    const int b   = blockIdx.z;
    const int q0  = blockIdx.y * 4;
    const int v4b = blockIdx.x * 32;   // float4 col base (128 floats of v)

    const float4* attn4 = reinterpret_cast<const float4*>(attn) + (size_t)(b * 64 + q0) * 128;
#pragma unroll
    for (int p = 0; p < 2; ++p) {
        int u  = t + p * 256;          // 0..511
        int qr = u >> 7;               // 0..3
        int c4 = u & 127;              // 0..127
        *reinterpret_cast<float4*>(&attnS[qr][c4 * 4]) = attn4[qr * 128 + c4];
    }
    __syncthreads();

    const int kh = t >> 7;             // k-half: 0 or 1
    const int q  = (t >> 5) & 3;       // 0..3
    const int v4 = v4b + (t & 31);     // float4 col index (0..127)
    const float* arow = &attnS[q][kh * 256];
    const float4* vp = reinterpret_cast<const float4*>(values)
                     + ((size_t)b * 512 + (size_t)kh * 256) * 128 + v4;

    float ax = 0.f, ay = 0.f, az = 0.f, aw = 0.f;
    float4 n0 = vp[0], n1 = vp[128], n2 = vp[256], n3 = vp[384];
#pragma unroll 2
    for (int kk = 0; kk < 256; kk += 4) {
        float4 c0 = n0, c1 = n1, c2 = n2, c3 = n3;
        vp += 512;
        if (kk + 4 < 256) { n0 = vp[0]; n1 = vp[128]; n2 = vp[256]; n3 = vp[384]; }
        float4 a = *reinterpret_cast<const float4*>(&arow[kk]);
        ax = fmaf(a.x, c0.x, ax); ay = fmaf(a.x, c0.y, ay);
        az = fmaf(a.x, c0.z, az); aw = fmaf(a.x, c0.w, aw);
        ax = fmaf(a.y, c1.x, ax); ay = fmaf(a.y, c1.y, ay);
        az = fmaf(a.y, c1.z, az); aw = fmaf(a.y, c1.w, aw);
        ax = fmaf(a.z, c2.x, ax); ay = fmaf(a.z, c2.y, ay);
        az = fmaf(a.z, c2.z, az); aw = fmaf(a.z, c2.w, aw);
        ax = fmaf(a.w, c3.x, ax); ay = fmaf(a.w, c3.y, ay);
        az = fmaf(a.w, c3.z, az); aw = fmaf(a.w, c3.w, aw);
    }

    __syncthreads();                   // attnS reads done; reuse as reduction buf
    float* red = &attnS[0][0];         // 128 threads x 4 floats = 2 KB
    if (kh == 1) {
        float4 o; o.x = ax; o.y = ay; o.z = az; o.w = aw;
        *reinterpret_cast<float4*>(&red[(t - 128) * 4]) = o;
    }
    __syncthreads();
    if (kh == 0) {
        float4 o = *reinterpret_cast<const float4*>(&red[t * 4]);
        o.x += ax; o.y += ay; o.z += az; o.w += aw;
        reinterpret_cast<float4*>(out)[(size_t)(b * 64 + q0 + q) * 128 + v4] = o;
    }
}

// ---------------------------------------------------------------------------
extern "C" void kernel_launch(void* const* d_in, const int* in_sizes, int n_in,
                              void* d_out, int out_size, void* d_ws, size_t ws_size,
                              hipStream_t stream) {
    (void)in_sizes; (void)n_in; (void)out_size; (void)ws_size;
    const float* queries    = (const float*)d_in[0];   // [16,64,512]
    const float* keys       = (const float*)d_in[1];   // [16,512,512]
    const float* values     = (const float*)d_in[2];   // [16,512,512]
    const int*   valid_lens = (const int*)d_in[3];     // [16]
    const float* Wq         = (const float*)d_in[4];   // [512,256]
    const float* Wk         = (const float*)d_in[5];   // [512,256]
    const float* Wv         = (const float*)d_in[6];   // [256]
    float* out = (float*)d_out;                        // [16,64,512]

    float* ws    = (float*)d_ws;
    float* Eq    = ws;                         // [1024][256]        1 MB
    float* Ekp   = ws + 262144;                // [16][128][512][2]  8 MB
    float* attn  = ws + 262144 + 2097152;      // [16][64][512]      2 MB
    ushort* Wq2T = (ushort*)(ws + 2883584);    // [256][1536]        0.75 MB
    ushort* Wk2T = Wq2T + 393216;              // [256][1536]        0.75 MB

    hipLaunchKernelGGL(wprep_kernel, dim3(8, 4, 2), dim3(256), 0, stream,
                       Wq, Wk, Wq2T, Wk2T);
    hipLaunchKernelGGL(mfma_proj_kernel, dim3(72, 4), dim3(256), 0, stream,
                       queries, keys, Wq2T, Wk2T, Eq, Ekp);
    hipLaunchKernelGGL(score_softmax_kernel, dim3(512), dim3(256), 0, stream,
                       Eq, Ekp, Wv, valid_lens, attn);
    hipLaunchKernelGGL(pv_kernel, dim3(4, 16, 16), dim3(256), 0, stream, attn, values, out);
}

// Round 7
// 153.754 us; speedup vs baseline: 1.4366x; 1.0808x over previous
//
#include <hip/hip_runtime.h>

// Problem dims: B=16, Q=64, K=512, DQ=DK=DV=512, H=256
#define LOG2E 1.4426950408889634f
#define TWO_LOG2E 2.8853900817779268f

typedef __attribute__((ext_vector_type(8))) short short8;   // bf16x8 MFMA frag
typedef __attribute__((ext_vector_type(4))) float f32x4;    // MFMA acc

__device__ __forceinline__ float e2x(float v) {
    // exp2(2*log2(e)*v) == e^{2v}
    return __builtin_amdgcn_exp2f(v * TWO_LOG2E);
}

// Exact fp32 -> (hi,lo) bf16 split, packed: hi = top16(f) (truncation, exact),
// lo = f - hi (exactly representable in bf16: <=8 significand bits).
__device__ __forceinline__ void split2(float x, float y, unsigned& hi, unsigned& lo) {
    unsigned ux = __float_as_uint(x), uy = __float_as_uint(y);
    float hx = __uint_as_float(ux & 0xffff0000u);
    float hy = __uint_as_float(uy & 0xffff0000u);
    unsigned lx = __float_as_uint(x - hx), ly = __float_as_uint(y - hy);
    hi = (ux >> 16) | (uy & 0xffff0000u);
    lo = (lx >> 16) | (ly & 0xffff0000u);
}

// ---------------------------------------------------------------------------
// Kernel 0: W2T[n][k'] split/transposed weights, chunk-interleaved (unchanged)
// ---------------------------------------------------------------------------
__global__ __launch_bounds__(256) void wprep_kernel(const float* __restrict__ Wq,
                                                    const float* __restrict__ Wk,
                                                    ushort* __restrict__ Wq2T,
                                                    ushort* __restrict__ Wk2T) {
    __shared__ float T[64][65];
    const float* W  = blockIdx.z ? Wk : Wq;
    ushort* W2T     = blockIdx.z ? Wk2T : Wq2T;
    const int t  = threadIdx.x;
    const int k0 = blockIdx.x * 64;
    const int n0 = blockIdx.y * 64;
#pragma unroll
    for (int p = 0; p < 4; ++p) {
        int u  = t + p * 256;          // 0..1023
        int kk = u >> 4;               // 0..63
        int nf = (u & 15) * 4;
        float4 w = *reinterpret_cast<const float4*>(&W[(size_t)(k0 + kk) * 256 + n0 + nf]);
        T[nf + 0][kk] = w.x; T[nf + 1][kk] = w.y;
        T[nf + 2][kk] = w.z; T[nf + 3][kk] = w.w;
    }
    __syncthreads();
#pragma unroll
    for (int p = 0; p < 4; ++p) {
        int u  = t + p * 256;
        int n  = u >> 4;               // 0..63
        int kf = (u & 15) * 4;         // 0..60
        float a = T[n][kf], b = T[n][kf + 1], c = T[n][kf + 2], d = T[n][kf + 3];
        unsigned h01, l01, h23, l23;
        split2(a, b, h01, l01);
        split2(c, d, h23, l23);
        int kg = k0 + kf;
        ushort* row = W2T + (size_t)(n0 + n) * 1536 + (kg >> 5) * 96 + (kg & 31);
        uint2 hi; hi.x = h01; hi.y = h23;
        uint2 lo; lo.x = l01; lo.y = l23;
        *reinterpret_cast<uint2*>(row)      = hi;   // seg0: hi
        *reinterpret_cast<uint2*>(row + 32) = hi;   // seg1: hi
        *reinterpret_cast<uint2*>(row + 64) = lo;   // seg2: lo
    }
}

// ---------------------------------------------------------------------------
// Kernel 1: fused MFMA projection (unchanged)
// ---------------------------------------------------------------------------
__global__ __launch_bounds__(256) void mfma_proj_kernel(const float* __restrict__ queries,
                                                        const float* __restrict__ keys,
                                                        const ushort* __restrict__ Wq2T,
                                                        const ushort* __restrict__ Wk2T,
                                                        float* __restrict__ Eq,
                                                        float* __restrict__ Ekp) {
    __shared__ float smemf[9216];            // 36864 B: Ah(24576) + Ws(12288); reused as Cs
    ushort* Ah = reinterpret_cast<ushort*>(smemf);           // [128 m][96 k']
    ushort* Ws = reinterpret_cast<ushort*>(smemf) + 12288;   // [64 n][96 k']

    const int t    = threadIdx.x;
    const int mt   = blockIdx.x;             // 0..71
    const int Nb   = blockIdx.y * 64;
    const bool isQ = mt < 8;
    const int Mb   = mt * 128;
    const float4* Asrc4 = reinterpret_cast<const float4*>(isQ ? queries : keys)
                        + (size_t)(isQ ? Mb : Mb - 1024) * 128;
    const ushort* W2T = isQ ? Wq2T : Wk2T;

    const int ln15 = t & 15;
    const int q    = (t >> 4) & 3;
    const int w    = t >> 6;
    const int wm   = (w >> 1) * 64;          // wave m-offset
    const int wn   = (w & 1) * 32;           // wave n-offset

    int bn[3], brem[3];
#pragma unroll
    for (int i = 0; i < 3; ++i) {
        int o   = i * 4096 + (t >> 6) * 1024 + (t & 63) * 16;  // linear byte in Ws
        bn[i]   = o / 192;                   // n row (192 B per row)
        brem[i] = o - bn[i] * 192;           // byte within row
    }
    const char* gB[3];
#pragma unroll
    for (int i = 0; i < 3; ++i)
        gB[i] = reinterpret_cast<const char*>(W2T) + (size_t)(Nb + bn[i]) * 3072 + brem[i];

    f32x4 acc[4][2];
#pragma unroll
    for (int fm = 0; fm < 4; ++fm)
#pragma unroll
        for (int fn = 0; fn < 2; ++fn) acc[fm][fn] = (f32x4)0.0f;

    for (int c = 0; c < 16; ++c) {
        __syncthreads();                     // previous chunk's LDS reads done
#pragma unroll
        for (int p = 0; p < 4; ++p) {
            int u  = t + p * 256;            // 0..1023
            int m  = u >> 3;                 // 0..127
            int kf = (u & 7) * 4;            // 0..28
            float4 a = Asrc4[(size_t)m * 128 + c * 8 + (u & 7)];
            unsigned h01, l01, h23, l23;
            split2(a.x, a.y, h01, l01);
            split2(a.z, a.w, h23, l23);
            uint2 hi; hi.x = h01; hi.y = h23;
            uint2 lo; lo.x = l01; lo.y = l23;
            ushort* row = Ah + m * 96 + kf;
            *reinterpret_cast<uint2*>(row)      = hi;
            *reinterpret_cast<uint2*>(row + 32) = lo;
            *reinterpret_cast<uint2*>(row + 64) = hi;
        }
#pragma unroll
        for (int i = 0; i < 3; ++i) {
            __builtin_amdgcn_global_load_lds(
                reinterpret_cast<const unsigned int*>(gB[i]),
                reinterpret_cast<unsigned int*>(
                    reinterpret_cast<char*>(Ws) + i * 4096 + (t >> 6) * 1024),
                16, 0, 0);
            gB[i] += 192;
        }
        __syncthreads();                     // drains vmcnt + lgkm
#pragma unroll
        for (int s = 0; s < 3; ++s) {
            short8 af[4], bf[2];
#pragma unroll
            for (int fm = 0; fm < 4; ++fm)
                af[fm] = *reinterpret_cast<const short8*>(
                    Ah + (wm + fm * 16 + ln15) * 96 + s * 32 + q * 8);
#pragma unroll
            for (int fn = 0; fn < 2; ++fn)
                bf[fn] = *reinterpret_cast<const short8*>(
                    Ws + (wn + fn * 16 + ln15) * 96 + s * 32 + q * 8);
#pragma unroll
            for (int fm = 0; fm < 4; ++fm)
#pragma unroll
                for (int fn = 0; fn < 2; ++fn)
                    acc[fm][fn] = __builtin_amdgcn_mfma_f32_16x16x32_bf16(
                        af[fm], bf[fn], acc[fm][fn], 0, 0, 0);
        }
    }

    if (isQ) {
#pragma unroll
        for (int fm = 0; fm < 4; ++fm)
#pragma unroll
            for (int fn = 0; fn < 2; ++fn)
#pragma unroll
                for (int r = 0; r < 4; ++r) {
                    int row = Mb + wm + fm * 16 + q * 4 + r;
                    int col = Nb + wn + fn * 16 + ln15;
                    Eq[(size_t)row * 256 + col] = e2x(acc[fm][fn][r]);
                }
    } else {
        __syncthreads();
        float (*Cs)[131] = reinterpret_cast<float(*)[131]>(smemf);  // [n 64][m 128]
#pragma unroll
        for (int fm = 0; fm < 4; ++fm)
#pragma unroll
            for (int fn = 0; fn < 2; ++fn)
#pragma unroll
                for (int r = 0; r < 4; ++r) {
                    int m_l = wm + fm * 16 + q * 4 + r;
                    int n_l = wn + fn * 16 + ln15;
                    Cs[n_l][m_l] = acc[fm][fn][r];
                }
        __syncthreads();
        const int rk     = Mb - 1024;        // flat (b,k) base
        const int b      = rk >> 9;
        const int k0h    = (rk & 511) >> 1;
        const int h2base = Nb >> 1;
        float4* out4 = reinterpret_cast<float4*>(Ekp);
#pragma unroll
        for (int p = 0; p < 8; ++p) {
            int u   = t + p * 256;           // 0..2047
            int h2r = u >> 6;                // 0..31
            int kp  = u & 63;                // k-pair 0..63
            int kk  = kp * 2;
            float4 o;
            o.x = e2x(Cs[2 * h2r    ][kk    ]);
            o.y = e2x(Cs[2 * h2r + 1][kk    ]);
            o.z = e2x(Cs[2 * h2r    ][kk + 1]);
            o.w = e2x(Cs[2 * h2r + 1][kk + 1]);
            out4[(size_t)b * 32768 + (size_t)(h2base + h2r) * 256 + k0h + kp] = o;
        }
    }
}

// ---------------------------------------------------------------------------
// Kernel 2: scores + masked softmax -> attn[b][q][k]   (unchanged)
// ---------------------------------------------------------------------------
__global__ __launch_bounds__(256) void score_softmax_kernel(
        const float* __restrict__ Eq, const float* __restrict__ Ekp,
        const float* __restrict__ Wv, const int* __restrict__ valid_lens,
        float* __restrict__ attn) {
    __shared__ float redmA[4], redmB[4], redlA[4], redlB[4];

    const int t  = threadIdx.x;
    const int bq = blockIdx.x;        // 0..511
    const int b  = bq >> 5;
    const int q0 = (bq & 31) * 2;

    const float* eqA = Eq + (size_t)(b * 64 + q0) * 256;
    const float* eqB = eqA + 256;
    const float4* ek4 = reinterpret_cast<const float4*>(Ekp) + (size_t)b * 32768 + t;

    float accA0 = 0.f, accA1 = 0.f, accB0 = 0.f, accB1 = 0.f;
#pragma unroll 4
    for (int h2 = 0; h2 < 128; ++h2) {
        const float4 ek = ek4[h2 * 256];
        const float w0 = Wv[2 * h2];
        const float w1 = Wv[2 * h2 + 1];
        {
            const float e0 = eqA[2 * h2], e1 = eqA[2 * h2 + 1];
            float a00 = fmaf(e0, ek.x, 1.0f);
            float a10 = fmaf(e1, ek.y, 1.0f);
            float a01 = fmaf(e0, ek.z, 1.0f);
            float a11 = fmaf(e1, ek.w, 1.0f);
            float d0 = a00 * a10, d1 = a01 * a11;
            float n0 = fmaf(w1, a00, w0 * a10);
            float n1 = fmaf(w1, a01, w0 * a11);
            accA0 = fmaf(n0, __builtin_amdgcn_rcpf(d0), accA0);
            accA1 = fmaf(n1, __builtin_amdgcn_rcpf(d1), accA1);
        }
        {
            const float e0 = eqB[2 * h2], e1 = eqB[2 * h2 + 1];
            float a00 = fmaf(e0, ek.x, 1.0f);
            float a10 = fmaf(e1, ek.y, 1.0f);
            float a01 = fmaf(e0, ek.z, 1.0f);
            float a11 = fmaf(e1, ek.w, 1.0f);
            float d0 = a00 * a10, d1 = a01 * a11;
            float n0 = fmaf(w1, a00, w0 * a10);
            float n1 = fmaf(w1, a01, w0 * a11);
            accB0 = fmaf(n0, __builtin_amdgcn_rcpf(d0), accB0);
            accB1 = fmaf(n1, __builtin_amdgcn_rcpf(d1), accB1);
        }
    }
    float sA0 = -2.0f * accA0, sA1 = -2.0f * accA1;
    float sB0 = -2.0f * accB0, sB1 = -2.0f * accB1;
    const int vl = valid_lens[b];
    const int k0 = 2 * t;
    if (k0     >= vl) { sA0 = -1e6f; sB0 = -1e6f; }
    if (k0 + 1 >= vl) { sA1 = -1e6f; sB1 = -1e6f; }

    const int w = t >> 6;
    float mA = fmaxf(sA0, sA1);
    float mB = fmaxf(sB0, sB1);
#pragma unroll
    for (int off = 32; off > 0; off >>= 1) {
        mA = fmaxf(mA, __shfl_xor(mA, off));
        mB = fmaxf(mB, __shfl_xor(mB, off));
    }
    if ((t & 63) == 0) { redmA[w] = mA; redmB[w] = mB; }
    __syncthreads();
    mA = fmaxf(fmaxf(redmA[0], redmA[1]), fmaxf(redmA[2], redmA[3]));
    mB = fmaxf(fmaxf(redmB[0], redmB[1]), fmaxf(redmB[2], redmB[3]));

    float pA0 = __builtin_amdgcn_exp2f((sA0 - mA) * LOG2E);
    float pA1 = __builtin_amdgcn_exp2f((sA1 - mA) * LOG2E);
    float pB0 = __builtin_amdgcn_exp2f((sB0 - mB) * LOG2E);
    float pB1 = __builtin_amdgcn_exp2f((sB1 - mB) * LOG2E);
    float lA = pA0 + pA1, lB = pB0 + pB1;
#pragma unroll
    for (int off = 32; off > 0; off >>= 1) {
        lA += __shfl_xor(lA, off);
        lB += __shfl_xor(lB, off);
    }
    if ((t & 63) == 0) { redlA[w] = lA; redlB[w] = lB; }
    __syncthreads();
    lA = (redlA[0] + redlA[1]) + (redlA[2] + redlA[3]);
    lB = (redlB[0] + redlB[1]) + (redlB[2] + redlB[3]);
    const float invA = 1.0f / lA;
    const float invB = 1.0f / lB;

    float2* attn2 = reinterpret_cast<float2*>(attn);
    float2 oA; oA.x = pA0 * invA; oA.y = pA1 * invA;
    float2 oB; oB.x = pB0 * invB; oB.y = pB1 * invB;
    attn2[(size_t)(b * 64 + q0) * 256 + t]       = oA;
    attn2[(size_t)(b * 64 + q0 + 1) * 256 + t]   = oB;
}

// ---------------------------------------------------------------------------
// Kernel 3 (REWRITTEN): out[b][q][v] = attn[b][q][:] @ values[b][:][v]
// Block = (b, 32q, 64v); grid (8 v-tiles, 2 q-tiles, 16 b) = 256 = 1/CU.
// K-loop: 8 chunks of 64 k; Ps[32][68] + Vs[64][68] staged in LDS with
// register double-buffered global prefetch (chunk c+1 loads fly during
// chunk c compute). Wave = 8 q-rows; lane = (v4 0..15, ksub 0..3), ksub
// interleaved at k-quad granularity; shfl_xor(16/32) combines ksub partials.
// ---------------------------------------------------------------------------
__global__ __launch_bounds__(256) void pv_kernel(const float* __restrict__ attn,
                                                 const float* __restrict__ values,
                                                 float* __restrict__ out) {
    __shared__ __align__(16) float Ps[32][68];   // [q][k-chunk]   8704 B
    __shared__ __align__(16) float Vs[64][68];   // [k][v-chunk]  17408 B

    const int t  = threadIdx.x;
    const int b  = blockIdx.z;
    const int q0 = blockIdx.y * 32;
    const int vt = blockIdx.x;                   // v-tile: 64 floats = 16 f4

    const float4* attn4 = reinterpret_cast<const float4*>(attn) + (size_t)(b * 64 + q0) * 128;
    const float4* val4  = reinterpret_cast<const float4*>(values) + (size_t)b * 512 * 128 + vt * 16;

    const int lane = t & 63;
    const int w    = t >> 6;       // wave -> q-octet
    const int v4   = lane & 15;
    const int ksub = lane >> 4;

    // staging maps (same for every chunk)
    const int pq = t >> 4;         // 0..15 -> rows 0..15 (i=0), 16..31 (i=1)? no:
    // u = t + i*256: row = u>>4 (0..31), col4 = u&15
    float4 rp[2], rv[4];

#pragma unroll
    for (int i = 0; i < 2; ++i) {
        int u = t + i * 256;
        rp[i] = attn4[(size_t)(u >> 4) * 128 + (u & 15)];
    }
#pragma unroll
    for (int i = 0; i < 4; ++i) {
        int u = t + i * 256;
        rv[i] = val4[(size_t)(u >> 4) * 128 + (u & 15)];
    }

    float4 acc[8];
#pragma unroll
    for (int j = 0; j < 8; ++j) acc[j] = make_float4(0.f, 0.f, 0.f, 0.f);

    for (int c = 0; c < 8; ++c) {
        __syncthreads();                         // prev chunk's LDS reads done
#pragma unroll
        for (int i = 0; i < 2; ++i) {
            int u = t + i * 256;
            *reinterpret_cast<float4*>(&Ps[u >> 4][(u & 15) * 4]) = rp[i];
        }
#pragma unroll
        for (int i = 0; i < 4; ++i) {
            int u = t + i * 256;
            *reinterpret_cast<float4*>(&Vs[u >> 4][(u & 15) * 4]) = rv[i];
        }
        __syncthreads();
        if (c < 7) {                             // prefetch chunk c+1
            int kf4 = (c + 1) * 16;              // chunk base in f4 units
#pragma unroll
            for (int i = 0; i < 2; ++i) {
                int u = t + i * 256;
                rp[i] = attn4[(size_t)(u >> 4) * 128 + kf4 + (u & 15)];
            }
#pragma unroll
            for (int i = 0; i < 4; ++i) {
                int u = t + i * 256;
                rv[i] = val4[(size_t)((c + 1) * 64 + (u >> 4)) * 128 + (u & 15)];
            }
        }
        // compute: lane covers k = kk*16 + ksub*4 + {0..3}, kk = 0..3
#pragma unroll
        for (int kk = 0; kk < 4; ++kk) {
            int kb = kk * 16 + ksub * 4;
            float4 V0 = *reinterpret_cast<const float4*>(&Vs[kb + 0][v4 * 4]);
            float4 V1 = *reinterpret_cast<const float4*>(&Vs[kb + 1][v4 * 4]);
            float4 V2 = *reinterpret_cast<const float4*>(&Vs[kb + 2][v4 * 4]);
            float4 V3 = *reinterpret_cast<const float4*>(&Vs[kb + 3][v4 * 4]);
#pragma unroll
            for (int j = 0; j < 8; ++j) {
                float4 p4 = *reinterpret_cast<const float4*>(&Ps[w * 8 + j][kb]);
                acc[j].x = fmaf(p4.x, V0.x, acc[j].x);
                acc[j].y = fmaf(p4.x, V0.y, acc[j].y);
                acc[j].z = fmaf(p4.x, V0.z, acc[j].z);
                acc[j].w = fmaf(p4.x, V0.w, acc[j].w);
                acc[j].x = fmaf(p4.y, V1.x, acc[j].x);
                acc[j].y = fmaf(p4.y, V1.y, acc[j].y);
                acc[j].z = fmaf(p4.y, V1.z, acc[j].z);
                acc[j].w = fmaf(p4.y, V1.w, acc[j].w);
                acc[j].x = fmaf(p4.z, V2.x, acc[j].x);
                acc[j].y = fmaf(p4.z, V2.y, acc[j].y);
                acc[j].z = fmaf(p4.z, V2.z, acc[j].z);
                acc[j].w = fmaf(p4.z, V2.w, acc[j].w);
                acc[j].x = fmaf(p4.w, V3.x, acc[j].x);
                acc[j].y = fmaf(p4.w, V3.y, acc[j].y);
                acc[j].z = fmaf(p4.w, V3.z, acc[j].z);
                acc[j].w = fmaf(p4.w, V3.w, acc[j].w);
            }
        }
    }

    // combine the 4 ksub partials (butterfly over lane bits 4,5)
#pragma unroll
    for (int j = 0; j < 8; ++j) {
        acc[j].x += __shfl_xor(acc[j].x, 16);
        acc[j].y += __shfl_xor(acc[j].y, 16);
        acc[j].z += __shfl_xor(acc[j].z, 16);
        acc[j].w += __shfl_xor(acc[j].w, 16);
        acc[j].x += __shfl_xor(acc[j].x, 32);
        acc[j].y += __shfl_xor(acc[j].y, 32);
        acc[j].z += __shfl_xor(acc[j].z, 32);
        acc[j].w += __shfl_xor(acc[j].w, 32);
    }
    if (ksub == 0) {
        float4* out4 = reinterpret_cast<float4*>(out);
#pragma unroll
        for (int j = 0; j < 8; ++j)
            out4[(size_t)(b * 64 + q0 + w * 8 + j) * 128 + vt * 16 + v4] = acc[j];
    }
}

// ---------------------------------------------------------------------------
extern "C" void kernel_launch(void* const* d_in, const int* in_sizes, int n_in,
                              void* d_out, int out_size, void* d_ws, size_t ws_size,
                              hipStream_t stream) {
    (void)in_sizes; (void)n_in; (void)out_size; (void)ws_size;
    const float* queries    = (const float*)d_in[0];   // [16,64,512]
    const float* keys       = (const float*)d_in[1];   // [16,512,512]
    const float* values     = (const float*)d_in[2];   // [16,512,512]
    const int*   valid_lens = (const int*)d_in[3];     // [16]
    const float* Wq         = (const float*)d_in[4];   // [512,256]
    const float* Wk         = (const float*)d_in[5];   // [512,256]
    const float* Wv         = (const float*)d_in[6];   // [256]
    float* out = (float*)d_out;                        // [16,64,512]

    float* ws    = (float*)d_ws;
    float* Eq    = ws;                         // [1024][256]        1 MB
    float* Ekp   = ws + 262144;                // [16][128][512][2]  8 MB
    float* attn  = ws + 262144 + 2097152;      // [16][64][512]      2 MB
    ushort* Wq2T = (ushort*)(ws + 2883584);    // [256][1536]        0.75 MB
    ushort* Wk2T = Wq2T + 393216;              // [256][1536]        0.75 MB

    hipLaunchKernelGGL(wprep_kernel, dim3(8, 4, 2), dim3(256), 0, stream,
                       Wq, Wk, Wq2T, Wk2T);
    hipLaunchKernelGGL(mfma_proj_kernel, dim3(72, 4), dim3(256), 0, stream,
                       queries, keys, Wq2T, Wk2T, Eq, Ekp);
    hipLaunchKernelGGL(score_softmax_kernel, dim3(512), dim3(256), 0, stream,
                       Eq, Ekp, Wv, valid_lens, attn);
    hipLaunchKernelGGL(pv_kernel, dim3(8, 2, 16), dim3(256), 0, stream, attn, values, out);
}